// Round 4
// baseline (216.322 us; speedup 1.0000x reference)
//
#include <hip/hip_runtime.h>
#include <hip/hip_fp16.h>
#include <math.h>

#define PI_F      3.14159265358979323846f
#define TWO_PI_F  6.28318530717958647692f
#define PI4_F     0.78539816339744830962f   // pi/4 == ROT_SCALE == 2pi/8

typedef _Float16 f16x8 __attribute__((ext_vector_type(8)));
typedef float    f32x4 __attribute__((ext_vector_type(4)));

#define KS_BYTES   (25 * 64 * 32 * 2)            // 102400 B
#define GUARD_OFF  KS_BYTES                      // 64 B of zeros
#define XH_OFF     ((size_t)1 << 20)             // 1 MB
#define XH_BYTES   ((size_t)8 * 256 * 256 * 32 * 2)   // 33.55 MB

__device__ __forceinline__ float sgn(float t) {
    return (t > 0.f) ? 1.f : ((t < 0.f) ? -1.f : 0.f);
}

__device__ __forceinline__ float b2(float x) {
    float a = x - 0.5f;
    float b = x - 1.5f;
    float c = 1.f + 2.f * x;
    float d = 3.f + 2.f * x;
    return (-3.f * a * a * sgn(0.5f - x)
            + b * b * sgn(1.5f - x)
            - 0.75f * c * c * sgn(0.5f + x)
            + 0.25f * d * d * sgn(1.5f + x)) * 0.25f;
}

// ks_h[t][O][I] fp16.  Also zeroes the 64 B OOB guard region.
__global__ void build_ks_kernel(const float* __restrict__ w, __half* __restrict__ ksh,
                                float* __restrict__ guard) {
    if (blockIdx.x == 0 && threadIdx.x < 16) guard[threadIdx.x] = 0.f;
    int g = blockIdx.x * 256 + threadIdx.x;
    if (g >= 64 * 32 * 25) return;
    int O = g & 63;
    int rest = g >> 6;
    int t = rest % 25;
    int I = rest / 25;
    int r0 = O >> 3, o = O & 7;
    int i = I >> 3, r = I & 7;
    int x = t / 5, y = t % 5;

    float theta = -(float)r0 * PI4_F;
    float cth = cosf(theta), sth = sinf(theta);
    float fx = (float)(x - 2), fy = (float)(y - 2);
    float xc = fx * cth - fy * sth;
    float yc = fx * sth + fy * cth;

    float rotv[8];
    float rs = (float)r * PI4_F + theta;
    #pragma unroll
    for (int mr = 0; mr < 8; ++mr) {
        float v = (float)mr * PI4_F - rs + PI_F;
        float md = fmodf(v, TWO_PI_F);
        if (md < 0.f) md += TWO_PI_F;
        rotv[mr] = b2((md - PI_F) / PI4_F);
    }

    float sum = 0.f;
    for (int mx = 0; mx < 25; ++mx) {
        float cx = (float)(mx / 5 - 2);
        float cy = (float)(mx % 5 - 2);
        float bx = b2(cx - xc) * b2(cy - yc);
        if (bx != 0.f) {
            const float* wp = w + (size_t)(i * 200 + mx * 8) * 8 + o;
            #pragma unroll
            for (int mr = 0; mr < 8; ++mr)
                sum = fmaf(bx * rotv[mr], wp[mr * 8], sum);
        }
    }
    ksh[(size_t)(t * 64 + O) * 32 + I] = __float2half(sum);
}

// X (b,32ch,256,256) f32  ->  Xh (b,256,256,32ch) fp16.  One block per (b, h-row).
__global__ __launch_bounds__(256, 2) void hwc_kernel(const float* __restrict__ X,
                                                     __half* __restrict__ Xh) {
    __shared__ float tl[32 * 260];
    int b = blockIdx.x >> 8;
    int h = blockIdx.x & 255;
    const float* Xb = X + ((size_t)b * 32) * 65536 + h * 256;
    int tid = threadIdx.x;

    for (int idx = tid; idx < 32 * 256; idx += 256) {
        int c = idx >> 8;
        int ww = idx & 255;
        tl[c * 260 + ww] = Xb[(size_t)c * 65536 + ww];
    }
    __syncthreads();

    uint4* dst = (uint4*)(Xh + ((size_t)(b * 65536 + h * 256 + tid)) * 32);
    #pragma unroll
    for (int kk = 0; kk < 4; ++kk) {
        union { __half hh[8]; uint4 u; } pk;
        #pragma unroll
        for (int j = 0; j < 8; ++j)
            pk.hh[j] = __float2half(tl[(kk * 8 + j) * 260 + tid]);
        dst[kk] = pk.u;
    }
}

// Pipelined implicit-GEMM conv. 256 blocks (1/CU), 512 threads (8 waves).
// Block owns a 16h x 128w strip; loops over 4 subtiles of 16x32 px with
// double-buffered LDS staged via global_load_lds DMA (16 B/lane).
__global__ __launch_bounds__(512, 1) void conv_hwc_kernel(const __half* __restrict__ Xh,
                                                          const __half* __restrict__ ksh,
                                                          const __half* __restrict__ guard,
                                                          float* __restrict__ out) {
    __shared__ uint4 xt[2 * 2880];   // 2 x 46.08 KB, [px(20*36)][slot(4x16B)] linear

    int blk = blockIdx.x;
    int b   = blk >> 5;
    int rem = blk & 31;
    int h0  = (rem >> 1) << 4;       // 16 h-strips
    int w0  = (rem & 1) << 7;        // 2 w-strips of 128
    int tid = threadIdx.x;
    int wave = tid >> 6, lane = tid & 63;
    int lpx = lane >> 2, slot = lane & 3;
    int lO = lane & 15, ks4 = lane >> 4;
    int bidx = lO * 4 + ks4;

    const uint4* ksq = (const uint4*)ksh;
    const char* Xb = (const char*)Xh + (size_t)b * (65536 * 64);   // 64 B per px
    const char* gp = (const char*)guard;

    // wave-cooperative DMA stage of subtile s into dst (2880 uint4, linear)
    auto stage = [&](int s, uint4* dst) {
        int w0s = w0 + s * 32;
        for (int j = wave; j < 45; j += 8) {
            int px = j * 16 + lpx;               // 0..719
            int r = px / 36;
            int c = px - r * 36;
            int gh = h0 + r - 2;
            int gw = w0s + c - 2;
            const char* src = ((unsigned)gh < 256u && (unsigned)gw < 256u)
                ? Xb + ((size_t)(gh * 256 + gw)) * 64 + slot * 16
                : gp + slot * 16;
            __builtin_amdgcn_global_load_lds(
                (const __attribute__((address_space(1))) void*)src,
                (__attribute__((address_space(3))) void*)(dst + j * 64),
                16, 0, 0);
        }
    };

    int baseA[4];
    #pragma unroll
    for (int q = 0; q < 4; ++q) {
        int r_q = wave * 2 + (q >> 1);
        baseA[q] = (r_q * 36 + (q & 1) * 16 + lO) * 4 + ks4;
    }

    stage(0, xt);
    asm volatile("s_waitcnt vmcnt(0)" ::: "memory");
    __builtin_amdgcn_s_barrier();

    #pragma unroll 1
    for (int s = 0; s < 4; ++s) {
        uint4* cbuf = xt + (s & 1) * 2880;
        uint4* nbuf = xt + ((s & 1) ^ 1) * 2880;
        if (s < 3) stage(s + 1, nbuf);

        f32x4 acc[4][4] = {};
        f16x8 Af[2][4], Bf[2][4];
        #pragma unroll
        for (int q = 0; q < 4; ++q)
            Af[0][q] = __builtin_bit_cast(f16x8, cbuf[baseA[q]]);
        #pragma unroll
        for (int n = 0; n < 4; ++n)
            Bf[0][n] = __builtin_bit_cast(f16x8, ksq[n * 64 + bidx]);

        #pragma unroll
        for (int t = 0; t < 25; ++t) {
            const int cur = t & 1, nxt = cur ^ 1;
            if (t < 24) {
                const int t1 = t + 1;
                const int aoff = ((t1 / 5) * 36 + (t1 % 5)) * 4;
                #pragma unroll
                for (int q = 0; q < 4; ++q)
                    Af[nxt][q] = __builtin_bit_cast(f16x8, cbuf[baseA[q] + aoff]);
                #pragma unroll
                for (int n = 0; n < 4; ++n)
                    Bf[nxt][n] = __builtin_bit_cast(f16x8, ksq[t1 * 256 + n * 64 + bidx]);
            }
            __builtin_amdgcn_s_setprio(1);
            #pragma unroll
            for (int q = 0; q < 4; ++q) {
                #pragma unroll
                for (int n = 0; n < 4; ++n)
                    acc[q][n] = __builtin_amdgcn_mfma_f32_16x16x32_f16(Af[cur][q], Bf[cur][n], acc[q][n], 0, 0, 0);
            }
            __builtin_amdgcn_s_setprio(0);
        }

        // stores: out[b][O&7][O>>3][h][w] * (2pi/8) — exactly 16 dwordx4, newest VMEM ops
        int w0s = w0 + s * 32;
        #pragma unroll
        for (int q = 0; q < 4; ++q) {
            int gh  = h0 + wave * 2 + (q >> 1);
            int gwb = w0s + (q & 1) * 16 + ks4 * 4;
            #pragma unroll
            for (int n = 0; n < 4; ++n) {
                int O = n * 16 + lO;
                float* op = out + (((size_t)(b * 8 + (O & 7)) * 8 + (O >> 3)) << 16)
                                + gh * 256 + gwb;
                *(f32x4*)op = acc[q][n] * PI4_F;
            }
        }

        if (s < 3) {
            // stores are the 16 newest VMEM ops -> vmcnt(16) guarantees the stage
            // DMA (older) completed without draining the output stores.
            asm volatile("s_waitcnt vmcnt(16) lgkmcnt(0)" ::: "memory");
            __builtin_amdgcn_s_barrier();
        }
    }
}

// ---- fallback (small ws): round-3 single-kernel conv reading f32 X ----
__global__ __launch_bounds__(512, 4) void conv_kernel_f32(const float* __restrict__ X,
                                                          const __half* __restrict__ ksh,
                                                          float* __restrict__ out) {
    __shared__ uint4 xt[720 * 5];
    int blk = blockIdx.x;
    int b = blk >> 7;
    int rem = blk & 127;
    int h0 = (rem >> 3) << 4;
    int w0 = (rem & 7) << 5;
    int tid = threadIdx.x;
    const float* Xb = X + (size_t)b * 32 * 65536;
    for (int lin = tid; lin < 2880; lin += 512) {
        int slotq = lin / 720;
        int pxi = lin - slotq * 720;
        int r = pxi / 36;
        int c = pxi - r * 36;
        int gh = h0 + r - 2;
        int gw = w0 + c - 2;
        union { __half h[8]; uint4 u; } pk;
        if ((unsigned)gh < 256u && (unsigned)gw < 256u) {
            const float* src = Xb + (size_t)slotq * 8 * 65536 + gh * 256 + gw;
            #pragma unroll
            for (int j = 0; j < 8; ++j) pk.h[j] = __float2half(src[j * 65536]);
        } else {
            pk.u = make_uint4(0u, 0u, 0u, 0u);
        }
        xt[pxi * 5 + slotq] = pk.u;
    }
    __syncthreads();
    int wave = tid >> 6, lane = tid & 63;
    int lO = lane & 15, ks4 = lane >> 4;
    const uint4* ksq = (const uint4*)ksh;
    int bidx = lO * 4 + ks4;
    f32x4 acc[4][4] = {};
    int baseA[4];
    #pragma unroll
    for (int q = 0; q < 4; ++q)
        baseA[q] = ((wave * 2 + (q >> 1)) * 36 + (q & 1) * 16 + lO) * 5 + ks4;
    f16x8 Bf[2][4];
    #pragma unroll
    for (int n = 0; n < 4; ++n)
        Bf[0][n] = __builtin_bit_cast(f16x8, ksq[n * 64 + bidx]);
    #pragma unroll
    for (int t = 0; t < 25; ++t) {
        const int cur = t & 1, nxt = cur ^ 1;
        f16x8 Af[4];
        #pragma unroll
        for (int q = 0; q < 4; ++q)
            Af[q] = __builtin_bit_cast(f16x8, xt[baseA[q] + ((t / 5) * 36 + (t % 5)) * 5]);
        if (t < 24) {
            #pragma unroll
            for (int n = 0; n < 4; ++n)
                Bf[nxt][n] = __builtin_bit_cast(f16x8, ksq[(t + 1) * 256 + n * 64 + bidx]);
        }
        #pragma unroll
        for (int q = 0; q < 4; ++q)
            #pragma unroll
            for (int n = 0; n < 4; ++n)
                acc[q][n] = __builtin_amdgcn_mfma_f32_16x16x32_f16(Af[q], Bf[cur][n], acc[q][n], 0, 0, 0);
    }
    #pragma unroll
    for (int q = 0; q < 4; ++q) {
        int gh = h0 + wave * 2 + (q >> 1);
        int gwb = w0 + (q & 1) * 16 + ks4 * 4;
        #pragma unroll
        for (int n = 0; n < 4; ++n) {
            int O = n * 16 + lO;
            float* op = out + (((size_t)(b * 8 + (O & 7)) * 8 + (O >> 3)) << 16) + gh * 256 + gwb;
            *(f32x4*)op = acc[q][n] * PI4_F;
        }
    }
}

extern "C" void kernel_launch(void* const* d_in, const int* in_sizes, int n_in,
                              void* d_out, int out_size, void* d_ws, size_t ws_size,
                              hipStream_t stream) {
    const float* X = (const float*)d_in[0];       // (8, 4, 8, 256, 256) f32
    const float* w = (const float*)d_in[1];       // (4, 200, 8) f32
    float* outp = (float*)d_out;                  // (8, 8, 8, 256, 256) f32
    char* ws = (char*)d_ws;
    __half* ksh = (__half*)ws;                    // 102.4 KB
    float* guard = (float*)(ws + GUARD_OFF);      // 64 B zeros

    build_ks_kernel<<<(64 * 32 * 25 + 255) / 256, 256, 0, stream>>>(w, ksh, guard);

    if (ws_size >= XH_OFF + XH_BYTES) {
        __half* Xh = (__half*)(ws + XH_OFF);      // 33.55 MB fp16 HWC
        hwc_kernel<<<8 * 256, 256, 0, stream>>>(X, Xh);
        conv_hwc_kernel<<<256, 512, 0, stream>>>(Xh, ksh, (const __half*)guard, outp);
    } else {
        conv_kernel_f32<<<8 * 16 * 8, 512, 0, stream>>>(X, ksh, outp);
    }
}

// Round 5
// 192.070 us; speedup vs baseline: 1.1263x; 1.1263x over previous
//
#include <hip/hip_runtime.h>
#include <hip/hip_fp16.h>
#include <math.h>

#define PI_F      3.14159265358979323846f
#define TWO_PI_F  6.28318530717958647692f
#define PI4_F     0.78539816339744830962f   // pi/4 == ROT_SCALE == 2pi/8

typedef _Float16 f16x8 __attribute__((ext_vector_type(8)));
typedef float    f32x4 __attribute__((ext_vector_type(4)));

#define KS_BYTES   (25 * 64 * 32 * 2)                 // 102400 B
#define XH_OFF     ((size_t)1 << 20)                  // 1 MB
#define XH_BYTES   ((size_t)8 * 256 * 256 * 32 * 2)   // 33.55 MB

__device__ __forceinline__ float sgn(float t) {
    return (t > 0.f) ? 1.f : ((t < 0.f) ? -1.f : 0.f);
}

__device__ __forceinline__ float b2(float x) {
    float a = x - 0.5f;
    float b = x - 1.5f;
    float c = 1.f + 2.f * x;
    float d = 3.f + 2.f * x;
    return (-3.f * a * a * sgn(0.5f - x)
            + b * b * sgn(1.5f - x)
            - 0.75f * c * c * sgn(0.5f + x)
            + 0.25f * d * d * sgn(1.5f + x)) * 0.25f;
}

// ks_h[t][O][I] fp16.  t = dx*5+dy, O = r0*8+o, I = i*8+r
__global__ void build_ks_kernel(const float* __restrict__ w, __half* __restrict__ ksh) {
    int g = blockIdx.x * 256 + threadIdx.x;
    if (g >= 64 * 32 * 25) return;
    int O = g & 63;
    int rest = g >> 6;
    int t = rest % 25;
    int I = rest / 25;
    int r0 = O >> 3, o = O & 7;
    int i = I >> 3, r = I & 7;
    int x = t / 5, y = t % 5;

    float theta = -(float)r0 * PI4_F;
    float cth = cosf(theta), sth = sinf(theta);
    float fx = (float)(x - 2), fy = (float)(y - 2);
    float xc = fx * cth - fy * sth;
    float yc = fx * sth + fy * cth;

    float rotv[8];
    float rs = (float)r * PI4_F + theta;
    #pragma unroll
    for (int mr = 0; mr < 8; ++mr) {
        float v = (float)mr * PI4_F - rs + PI_F;
        float md = fmodf(v, TWO_PI_F);
        if (md < 0.f) md += TWO_PI_F;
        rotv[mr] = b2((md - PI_F) / PI4_F);
    }

    float sum = 0.f;
    for (int mx = 0; mx < 25; ++mx) {
        float cx = (float)(mx / 5 - 2);
        float cy = (float)(mx % 5 - 2);
        float bx = b2(cx - xc) * b2(cy - yc);
        if (bx != 0.f) {
            const float* wp = w + (size_t)(i * 200 + mx * 8) * 8 + o;
            #pragma unroll
            for (int mr = 0; mr < 8; ++mr)
                sum = fmaf(bx * rotv[mr], wp[mr * 8], sum);
        }
    }
    ksh[(size_t)(t * 64 + O) * 32 + I] = __float2half(sum);
}

// X (b,32ch,256,256) f32  ->  Xh (b,256,256,32ch) fp16.  One block per (b, h-row).
__global__ __launch_bounds__(256, 2) void hwc_kernel(const float* __restrict__ X,
                                                     __half* __restrict__ Xh) {
    __shared__ float tl[32 * 260];
    int b = blockIdx.x >> 8;
    int h = blockIdx.x & 255;
    const float* Xb = X + ((size_t)b * 32) * 65536 + h * 256;
    int tid = threadIdx.x;

    for (int idx = tid; idx < 32 * 256; idx += 256) {
        int c = idx >> 8;
        int ww = idx & 255;
        tl[c * 260 + ww] = Xb[(size_t)c * 65536 + ww];
    }
    __syncthreads();

    uint4* dst = (uint4*)(Xh + ((size_t)(b * 65536 + h * 256 + tid)) * 32);
    #pragma unroll
    for (int kk = 0; kk < 4; ++kk) {
        union { __half hh[8]; uint4 u; } pk;
        #pragma unroll
        for (int j = 0; j < 8; ++j)
            pk.hh[j] = __float2half(tl[(kk * 8 + j) * 260 + tid]);
        dst[kk] = pk.u;
    }
}

// Implicit-GEMM conv, 16x16-px subtile per 256-thread block (4 waves).
// LDS xt: [px(20*20)][slot(5, 4 used)] uint4 = 32 KB -> up to 4 blocks/CU.
// Wave covers output rows wave*4+q (q 0..3); acc[4 q][4 n] over 64 O.
__global__ __launch_bounds__(256, 4) void conv_hwc_kernel(const __half* __restrict__ Xh,
                                                          const __half* __restrict__ ksh,
                                                          float* __restrict__ out) {
    __shared__ uint4 xt[2000];       // 20*20 px * 5 slots * 16 B = 32 KB

    int blk = blockIdx.x;
    int b   = blk >> 8;              // 8 batches
    int rem = blk & 255;
    int h0  = (rem >> 4) << 4;       // 16 h-strips of 16
    int w0  = (rem & 15) << 4;       // 16 w-strips of 16 (blk%8 -> XCD = w-col: vertical halo locality)
    int tid = threadIdx.x;

    const char* Xb = (const char*)Xh + (size_t)b * ((size_t)65536 * 64);

    // ---- stage: 1600 uint4, slot-minor (4 lanes = one px's 64 B, coalesced) ----
    #pragma unroll
    for (int k = 0; k < 7; ++k) {
        int lin = tid + k * 256;
        if (lin < 1600) {
            int px = lin >> 2, slot = lin & 3;
            int r = px / 20, c = px - r * 20;
            int gh = h0 + r - 2;
            int gw = w0 + c - 2;
            uint4 v = make_uint4(0u, 0u, 0u, 0u);
            if ((unsigned)gh < 256u && (unsigned)gw < 256u)
                v = *(const uint4*)(Xb + ((size_t)(gh * 256 + gw)) * 64 + slot * 16);
            xt[px * 5 + slot] = v;
        }
    }
    __syncthreads();

    int wave = tid >> 6, lane = tid & 63;
    int lO = lane & 15, ks4 = lane >> 4;
    int bidx = lO * 4 + ks4;
    const uint4* ksq = (const uint4*)ksh;

    f32x4 acc[4][4] = {};
    int baseA[4];
    #pragma unroll
    for (int q = 0; q < 4; ++q)
        baseA[q] = ((wave * 4 + q) * 20 + lO) * 5 + ks4;

    // ---- 25-tap fully-unrolled MFMA loop, A/B prefetch double-buffer ----
    f16x8 Af[2][4], Bf[2][4];
    #pragma unroll
    for (int q = 0; q < 4; ++q)
        Af[0][q] = __builtin_bit_cast(f16x8, xt[baseA[q]]);
    #pragma unroll
    for (int n = 0; n < 4; ++n)
        Bf[0][n] = __builtin_bit_cast(f16x8, ksq[n * 64 + bidx]);

    #pragma unroll
    for (int t = 0; t < 25; ++t) {
        const int cur = t & 1, nxt = cur ^ 1;
        if (t < 24) {
            const int t1 = t + 1;
            const int aoff = ((t1 / 5) * 20 + (t1 % 5)) * 5;
            #pragma unroll
            for (int q = 0; q < 4; ++q)
                Af[nxt][q] = __builtin_bit_cast(f16x8, xt[baseA[q] + aoff]);
            #pragma unroll
            for (int n = 0; n < 4; ++n)
                Bf[nxt][n] = __builtin_bit_cast(f16x8, ksq[t1 * 256 + n * 64 + bidx]);
        }
        __builtin_amdgcn_s_setprio(1);
        #pragma unroll
        for (int q = 0; q < 4; ++q) {
            #pragma unroll
            for (int n = 0; n < 4; ++n)
                acc[q][n] = __builtin_amdgcn_mfma_f32_16x16x32_f16(Af[cur][q], Bf[cur][n], acc[q][n], 0, 0, 0);
        }
        __builtin_amdgcn_s_setprio(0);
    }

    // ---- store: out[b][O&7][O>>3][h][w] * (2pi/8) ----
    #pragma unroll
    for (int q = 0; q < 4; ++q) {
        int gh  = h0 + wave * 4 + q;
        int gwb = w0 + ks4 * 4;
        #pragma unroll
        for (int n = 0; n < 4; ++n) {
            int O = n * 16 + lO;
            float* op = out + (((size_t)(b * 8 + (O & 7)) * 8 + (O >> 3)) << 16)
                            + gh * 256 + gwb;
            *(f32x4*)op = acc[q][n] * PI4_F;
        }
    }
}

// ---- fallback (small ws): round-3 single-kernel conv reading f32 X ----
__global__ __launch_bounds__(512, 4) void conv_kernel_f32(const float* __restrict__ X,
                                                          const __half* __restrict__ ksh,
                                                          float* __restrict__ out) {
    __shared__ uint4 xt[720 * 5];
    int blk = blockIdx.x;
    int b = blk >> 7;
    int rem = blk & 127;
    int h0 = (rem >> 3) << 4;
    int w0 = (rem & 7) << 5;
    int tid = threadIdx.x;
    const float* Xb = X + (size_t)b * 32 * 65536;
    for (int lin = tid; lin < 2880; lin += 512) {
        int slotq = lin / 720;
        int pxi = lin - slotq * 720;
        int r = pxi / 36;
        int c = pxi - r * 36;
        int gh = h0 + r - 2;
        int gw = w0 + c - 2;
        union { __half h[8]; uint4 u; } pk;
        if ((unsigned)gh < 256u && (unsigned)gw < 256u) {
            const float* src = Xb + (size_t)slotq * 8 * 65536 + gh * 256 + gw;
            #pragma unroll
            for (int j = 0; j < 8; ++j) pk.h[j] = __float2half(src[j * 65536]);
        } else {
            pk.u = make_uint4(0u, 0u, 0u, 0u);
        }
        xt[pxi * 5 + slotq] = pk.u;
    }
    __syncthreads();
    int wave = tid >> 6, lane = tid & 63;
    int lO = lane & 15, ks4 = lane >> 4;
    const uint4* ksq = (const uint4*)ksh;
    int bidx = lO * 4 + ks4;
    f32x4 acc[4][4] = {};
    int baseA[4];
    #pragma unroll
    for (int q = 0; q < 4; ++q)
        baseA[q] = ((wave * 2 + (q >> 1)) * 36 + (q & 1) * 16 + lO) * 5 + ks4;
    f16x8 Bf[2][4];
    #pragma unroll
    for (int n = 0; n < 4; ++n)
        Bf[0][n] = __builtin_bit_cast(f16x8, ksq[n * 64 + bidx]);
    #pragma unroll
    for (int t = 0; t < 25; ++t) {
        const int cur = t & 1, nxt = cur ^ 1;
        f16x8 Af[4];
        #pragma unroll
        for (int q = 0; q < 4; ++q)
            Af[q] = __builtin_bit_cast(f16x8, xt[baseA[q] + ((t / 5) * 36 + (t % 5)) * 5]);
        if (t < 24) {
            #pragma unroll
            for (int n = 0; n < 4; ++n)
                Bf[nxt][n] = __builtin_bit_cast(f16x8, ksq[(t + 1) * 256 + n * 64 + bidx]);
        }
        #pragma unroll
        for (int q = 0; q < 4; ++q)
            #pragma unroll
            for (int n = 0; n < 4; ++n)
                acc[q][n] = __builtin_amdgcn_mfma_f32_16x16x32_f16(Af[q], Bf[cur][n], acc[q][n], 0, 0, 0);
    }
    #pragma unroll
    for (int q = 0; q < 4; ++q) {
        int gh = h0 + wave * 2 + (q >> 1);
        int gwb = w0 + (q & 1) * 16 + ks4 * 4;
        #pragma unroll
        for (int n = 0; n < 4; ++n) {
            int O = n * 16 + lO;
            float* op = out + (((size_t)(b * 8 + (O & 7)) * 8 + (O >> 3)) << 16) + gh * 256 + gwb;
            *(f32x4*)op = acc[q][n] * PI4_F;
        }
    }
}

extern "C" void kernel_launch(void* const* d_in, const int* in_sizes, int n_in,
                              void* d_out, int out_size, void* d_ws, size_t ws_size,
                              hipStream_t stream) {
    const float* X = (const float*)d_in[0];       // (8, 4, 8, 256, 256) f32
    const float* w = (const float*)d_in[1];       // (4, 200, 8) f32
    float* outp = (float*)d_out;                  // (8, 8, 8, 256, 256) f32
    char* ws = (char*)d_ws;
    __half* ksh = (__half*)ws;                    // 102.4 KB

    build_ks_kernel<<<200, 256, 0, stream>>>(w, ksh);

    if (ws_size >= XH_OFF + XH_BYTES) {
        __half* Xh = (__half*)(ws + XH_OFF);      // 33.55 MB fp16 HWC
        hwc_kernel<<<8 * 256, 256, 0, stream>>>(X, Xh);
        conv_hwc_kernel<<<8 * 256, 256, 0, stream>>>(Xh, ksh, outp);
    } else {
        conv_kernel_f32<<<8 * 16 * 8, 512, 0, stream>>>(X, ksh, outp);
    }
}

// Round 6
// 176.734 us; speedup vs baseline: 1.2240x; 1.0868x over previous
//
#include <hip/hip_runtime.h>
#include <hip/hip_fp16.h>
#include <math.h>

#define PI_F      3.14159265358979323846f
#define TWO_PI_F  6.28318530717958647692f
#define PI4_F     0.78539816339744830962f   // pi/4 == ROT_SCALE == 2pi/8

typedef _Float16 f16x8 __attribute__((ext_vector_type(8)));
typedef float    f32x4 __attribute__((ext_vector_type(4)));

#define XH_OFF     ((size_t)1 << 20)                  // 1 MB
#define XH_BYTES   ((size_t)8 * 256 * 256 * 32 * 2)   // 33.55 MB

__device__ __forceinline__ float sgn(float t) {
    return (t > 0.f) ? 1.f : ((t < 0.f) ? -1.f : 0.f);
}

__device__ __forceinline__ float b2(float x) {
    float a = x - 0.5f;
    float b = x - 1.5f;
    float c = 1.f + 2.f * x;
    float d = 3.f + 2.f * x;
    return (-3.f * a * a * sgn(0.5f - x)
            + b * b * sgn(1.5f - x)
            - 0.75f * c * c * sgn(0.5f + x)
            + 0.25f * d * d * sgn(1.5f + x)) * 0.25f;
}

// ks_h[t][O][I] fp16.  t = dx*5+dy, O = r0*8+o, I = i*8+r
__global__ void build_ks_kernel(const float* __restrict__ w, __half* __restrict__ ksh) {
    int g = blockIdx.x * 256 + threadIdx.x;
    if (g >= 64 * 32 * 25) return;
    int O = g & 63;
    int rest = g >> 6;
    int t = rest % 25;
    int I = rest / 25;
    int r0 = O >> 3, o = O & 7;
    int i = I >> 3, r = I & 7;
    int x = t / 5, y = t % 5;

    float theta = -(float)r0 * PI4_F;
    float cth = cosf(theta), sth = sinf(theta);
    float fx = (float)(x - 2), fy = (float)(y - 2);
    float xc = fx * cth - fy * sth;
    float yc = fx * sth + fy * cth;

    float rotv[8];
    float rs = (float)r * PI4_F + theta;
    #pragma unroll
    for (int mr = 0; mr < 8; ++mr) {
        float v = (float)mr * PI4_F - rs + PI_F;
        float md = fmodf(v, TWO_PI_F);
        if (md < 0.f) md += TWO_PI_F;
        rotv[mr] = b2((md - PI_F) / PI4_F);
    }

    float sum = 0.f;
    for (int mx = 0; mx < 25; ++mx) {
        float cx = (float)(mx / 5 - 2);
        float cy = (float)(mx % 5 - 2);
        float bx = b2(cx - xc) * b2(cy - yc);
        if (bx != 0.f) {
            const float* wp = w + (size_t)(i * 200 + mx * 8) * 8 + o;
            #pragma unroll
            for (int mr = 0; mr < 8; ++mr)
                sum = fmaf(bx * rotv[mr], wp[mr * 8], sum);
        }
    }
    ksh[(size_t)(t * 64 + O) * 32 + I] = __float2half(sum);
}

// X (b,32ch,256,256) f32  ->  Xh (b,256,256,32ch) fp16.  One block per (b,h).
// Lane w: 32 coalesced plane reads, one 64 B packed write. No LDS needed.
__global__ __launch_bounds__(256, 4) void hwc_kernel(const float* __restrict__ X,
                                                     __half* __restrict__ Xh) {
    int b = blockIdx.x >> 8;
    int h = blockIdx.x & 255;
    int ww = threadIdx.x;
    const float* Xb = X + ((size_t)b * 32) * 65536 + h * 256 + ww;

    union { __half hh[8]; uint4 u; } pk[4];
    #pragma unroll
    for (int c = 0; c < 32; ++c)
        pk[c >> 3].hh[c & 7] = __float2half(Xb[(size_t)c * 65536]);

    uint4* dst = (uint4*)(Xh + ((size_t)(b * 65536 + h * 256 + ww)) * 32);
    #pragma unroll
    for (int kk = 0; kk < 4; ++kk) dst[kk] = pk[kk].u;
}

// Implicit-GEMM conv: 16h x 32w px tile, 512 threads (8 waves), all 64 O.
// LDS xt[slot(4)][px(720=20x36)] uint4, slot-plane pad 1 uint4 (46.1 KB).
// Stage: per px, 4 contiguous uint4 global loads (wave reads 4 KB dense),
// 4 conflict-free ds_write_b128 (lane-contiguous within a slot plane).
// A-read: xt[721*ks4 + pxbase+lO] -> 16 contiguous uint4 per ks4 group.
// bid swizzle: b = bid&7 so each XCD (round-robin bid%8) owns one batch.
__global__ __launch_bounds__(512, 4) void conv_hwc_kernel(const __half* __restrict__ Xh,
                                                          const __half* __restrict__ ksh,
                                                          float* __restrict__ out) {
    __shared__ uint4 xt[4 * 721];    // 46144 B

    int bid = blockIdx.x;
    int b   = bid & 7;               // batch == XCD (locality: Xh slice ~4.2 MB ~ L2)
    int rem = bid >> 3;              // 0..127
    int h0  = (rem >> 3) << 4;       // 16 h-strips of 16
    int w0  = (rem & 7) << 5;        // 8 w-strips of 32
    int tid = threadIdx.x;

    const char* Xb = (const char*)Xh + (size_t)b * ((size_t)65536 * 64);

    // ---- stage 720 px * 64 B ----
    for (int p = tid; p < 720; p += 512) {
        int r = p / 36, c = p - (p / 36) * 36;
        int gh = h0 + r - 2;
        int gw = w0 + c - 2;
        uint4 v0 = make_uint4(0u, 0u, 0u, 0u), v1 = v0, v2 = v0, v3 = v0;
        if ((unsigned)gh < 256u && (unsigned)gw < 256u) {
            const uint4* s = (const uint4*)(Xb + ((size_t)(gh * 256 + gw)) * 64);
            v0 = s[0]; v1 = s[1]; v2 = s[2]; v3 = s[3];
        }
        xt[0 * 721 + p] = v0;
        xt[1 * 721 + p] = v1;
        xt[2 * 721 + p] = v2;
        xt[3 * 721 + p] = v3;
    }
    __syncthreads();

    int wave = tid >> 6, lane = tid & 63;
    int lO = lane & 15, ks4 = lane >> 4;
    int bidx = lO * 4 + ks4;
    const uint4* ksq = (const uint4*)ksh;

    f32x4 acc[4][4] = {};
    int baseA[4];
    #pragma unroll
    for (int q = 0; q < 4; ++q)
        baseA[q] = 721 * ks4 + (wave * 2 + (q >> 1)) * 36 + (q & 1) * 16 + lO;

    // ---- 25-tap fully-unrolled MFMA loop, A/B prefetch double-buffer ----
    f16x8 Af[2][4], Bf[2][4];
    #pragma unroll
    for (int q = 0; q < 4; ++q)
        Af[0][q] = __builtin_bit_cast(f16x8, xt[baseA[q]]);
    #pragma unroll
    for (int n = 0; n < 4; ++n)
        Bf[0][n] = __builtin_bit_cast(f16x8, ksq[n * 64 + bidx]);

    #pragma unroll
    for (int t = 0; t < 25; ++t) {
        const int cur = t & 1, nxt = cur ^ 1;
        if (t < 24) {
            const int t1 = t + 1;
            const int aoff = (t1 / 5) * 36 + (t1 % 5);
            #pragma unroll
            for (int q = 0; q < 4; ++q)
                Af[nxt][q] = __builtin_bit_cast(f16x8, xt[baseA[q] + aoff]);
            #pragma unroll
            for (int n = 0; n < 4; ++n)
                Bf[nxt][n] = __builtin_bit_cast(f16x8, ksq[t1 * 256 + n * 64 + bidx]);
        }
        __builtin_amdgcn_s_setprio(1);
        #pragma unroll
        for (int q = 0; q < 4; ++q) {
            #pragma unroll
            for (int n = 0; n < 4; ++n)
                acc[q][n] = __builtin_amdgcn_mfma_f32_16x16x32_f16(Af[cur][q], Bf[cur][n], acc[q][n], 0, 0, 0);
        }
        __builtin_amdgcn_s_setprio(0);
    }

    // ---- store: out[b][O&7][O>>3][h][w] * (2pi/8); full 128-B lines per plane-row ----
    #pragma unroll
    for (int q = 0; q < 4; ++q) {
        int gh  = h0 + wave * 2 + (q >> 1);
        int gwb = w0 + (q & 1) * 16 + ks4 * 4;
        #pragma unroll
        for (int n = 0; n < 4; ++n) {
            int O = n * 16 + lO;
            float* op = out + (((size_t)(b * 8 + (O & 7)) * 8 + (O >> 3)) << 16)
                            + gh * 256 + gwb;
            *(f32x4*)op = acc[q][n] * PI4_F;
        }
    }
}

// ---- fallback (small ws): round-3 single-kernel conv reading f32 X ----
__global__ __launch_bounds__(512, 4) void conv_kernel_f32(const float* __restrict__ X,
                                                          const __half* __restrict__ ksh,
                                                          float* __restrict__ out) {
    __shared__ uint4 xt[720 * 5];
    int blk = blockIdx.x;
    int b = blk >> 7;
    int rem = blk & 127;
    int h0 = (rem >> 3) << 4;
    int w0 = (rem & 7) << 5;
    int tid = threadIdx.x;
    const float* Xb = X + (size_t)b * 32 * 65536;
    for (int lin = tid; lin < 2880; lin += 512) {
        int slotq = lin / 720;
        int pxi = lin - slotq * 720;
        int r = pxi / 36;
        int c = pxi - r * 36;
        int gh = h0 + r - 2;
        int gw = w0 + c - 2;
        union { __half h[8]; uint4 u; } pk;
        if ((unsigned)gh < 256u && (unsigned)gw < 256u) {
            const float* src = Xb + (size_t)slotq * 8 * 65536 + gh * 256 + gw;
            #pragma unroll
            for (int j = 0; j < 8; ++j) pk.h[j] = __float2half(src[j * 65536]);
        } else {
            pk.u = make_uint4(0u, 0u, 0u, 0u);
        }
        xt[pxi * 5 + slotq] = pk.u;
    }
    __syncthreads();
    int wave = tid >> 6, lane = tid & 63;
    int lO = lane & 15, ks4 = lane >> 4;
    const uint4* ksq = (const uint4*)ksh;
    int bidx = lO * 4 + ks4;
    f32x4 acc[4][4] = {};
    int baseA[4];
    #pragma unroll
    for (int q = 0; q < 4; ++q)
        baseA[q] = ((wave * 2 + (q >> 1)) * 36 + (q & 1) * 16 + lO) * 5 + ks4;
    f16x8 Bf[2][4];
    #pragma unroll
    for (int n = 0; n < 4; ++n)
        Bf[0][n] = __builtin_bit_cast(f16x8, ksq[n * 64 + bidx]);
    #pragma unroll
    for (int t = 0; t < 25; ++t) {
        const int cur = t & 1, nxt = cur ^ 1;
        f16x8 Af[4];
        #pragma unroll
        for (int q = 0; q < 4; ++q)
            Af[q] = __builtin_bit_cast(f16x8, xt[baseA[q] + ((t / 5) * 36 + (t % 5)) * 5]);
        if (t < 24) {
            #pragma unroll
            for (int n = 0; n < 4; ++n)
                Bf[nxt][n] = __builtin_bit_cast(f16x8, ksq[(t + 1) * 256 + n * 64 + bidx]);
        }
        #pragma unroll
        for (int q = 0; q < 4; ++q)
            #pragma unroll
            for (int n = 0; n < 4; ++n)
                acc[q][n] = __builtin_amdgcn_mfma_f32_16x16x32_f16(Af[q], Bf[cur][n], acc[q][n], 0, 0, 0);
    }
    #pragma unroll
    for (int q = 0; q < 4; ++q) {
        int gh = h0 + wave * 2 + (q >> 1);
        int gwb = w0 + (q & 1) * 16 + ks4 * 4;
        #pragma unroll
        for (int n = 0; n < 4; ++n) {
            int O = n * 16 + lO;
            float* op = out + (((size_t)(b * 8 + (O & 7)) * 8 + (O >> 3)) << 16) + gh * 256 + gwb;
            *(f32x4*)op = acc[q][n] * PI4_F;
        }
    }
}

extern "C" void kernel_launch(void* const* d_in, const int* in_sizes, int n_in,
                              void* d_out, int out_size, void* d_ws, size_t ws_size,
                              hipStream_t stream) {
    const float* X = (const float*)d_in[0];       // (8, 4, 8, 256, 256) f32
    const float* w = (const float*)d_in[1];       // (4, 200, 8) f32
    float* outp = (float*)d_out;                  // (8, 8, 8, 256, 256) f32
    char* ws = (char*)d_ws;
    __half* ksh = (__half*)ws;                    // 102.4 KB

    build_ks_kernel<<<200, 256, 0, stream>>>(w, ksh);

    if (ws_size >= XH_OFF + XH_BYTES) {
        __half* Xh = (__half*)(ws + XH_OFF);      // 33.55 MB fp16 HWC
        hwc_kernel<<<8 * 256, 256, 0, stream>>>(X, Xh);
        conv_hwc_kernel<<<8 * 128, 512, 0, stream>>>(Xh, ksh, outp);
    } else {
        conv_kernel_f32<<<8 * 16 * 8, 512, 0, stream>>>(X, ksh, outp);
    }
}

// Round 7
// 174.048 us; speedup vs baseline: 1.2429x; 1.0154x over previous
//
#include <hip/hip_runtime.h>
#include <hip/hip_fp16.h>
#include <math.h>

#define PI_F      3.14159265358979323846f
#define TWO_PI_F  6.28318530717958647692f
#define PI4_F     0.78539816339744830962f   // pi/4 == ROT_SCALE == 2pi/8

typedef _Float16 f16x8 __attribute__((ext_vector_type(8)));
typedef float    f32x4 __attribute__((ext_vector_type(4)));

#define XH_OFF     ((size_t)1 << 20)                  // 1 MB
#define XH_BYTES   ((size_t)8 * 256 * 256 * 32 * 2)   // 33.55 MB

__device__ __forceinline__ float sgn(float t) {
    return (t > 0.f) ? 1.f : ((t < 0.f) ? -1.f : 0.f);
}

__device__ __forceinline__ float b2(float x) {
    float a = x - 0.5f;
    float b = x - 1.5f;
    float c = 1.f + 2.f * x;
    float d = 3.f + 2.f * x;
    return (-3.f * a * a * sgn(0.5f - x)
            + b * b * sgn(1.5f - x)
            - 0.75f * c * c * sgn(0.5f + x)
            + 0.25f * d * d * sgn(1.5f + x)) * 0.25f;
}

// ks_h[t][O][I] fp16.  t = dx*5+dy, O = r0*8+o, I = i*8+r
__global__ void build_ks_kernel(const float* __restrict__ w, __half* __restrict__ ksh) {
    int g = blockIdx.x * 256 + threadIdx.x;
    if (g >= 64 * 32 * 25) return;
    int O = g & 63;
    int rest = g >> 6;
    int t = rest % 25;
    int I = rest / 25;
    int r0 = O >> 3, o = O & 7;
    int i = I >> 3, r = I & 7;
    int x = t / 5, y = t % 5;

    float theta = -(float)r0 * PI4_F;
    float cth = cosf(theta), sth = sinf(theta);
    float fx = (float)(x - 2), fy = (float)(y - 2);
    float xc = fx * cth - fy * sth;
    float yc = fx * sth + fy * cth;

    float rotv[8];
    float rs = (float)r * PI4_F + theta;
    #pragma unroll
    for (int mr = 0; mr < 8; ++mr) {
        float v = (float)mr * PI4_F - rs + PI_F;
        float md = fmodf(v, TWO_PI_F);
        if (md < 0.f) md += TWO_PI_F;
        rotv[mr] = b2((md - PI_F) / PI4_F);
    }

    float sum = 0.f;
    for (int mx = 0; mx < 25; ++mx) {
        float cx = (float)(mx / 5 - 2);
        float cy = (float)(mx % 5 - 2);
        float bx = b2(cx - xc) * b2(cy - yc);
        if (bx != 0.f) {
            const float* wp = w + (size_t)(i * 200 + mx * 8) * 8 + o;
            #pragma unroll
            for (int mr = 0; mr < 8; ++mr)
                sum = fmaf(bx * rotv[mr], wp[mr * 8], sum);
        }
    }
    ksh[(size_t)(t * 64 + O) * 32 + I] = __float2half(sum);
}

// X (b,32ch,256,256) f32  ->  Xh (b,256,256,32ch) fp16.  One block per (b,h).
// Lane w: 32 coalesced plane reads, one 64 B packed write. No LDS needed.
__global__ __launch_bounds__(256, 4) void hwc_kernel(const float* __restrict__ X,
                                                     __half* __restrict__ Xh) {
    int b = blockIdx.x >> 8;
    int h = blockIdx.x & 255;
    int ww = threadIdx.x;
    const float* Xb = X + ((size_t)b * 32) * 65536 + h * 256 + ww;

    union { __half hh[8]; uint4 u; } pk[4];
    #pragma unroll
    for (int c = 0; c < 32; ++c)
        pk[c >> 3].hh[c & 7] = __float2half(Xb[(size_t)c * 65536]);

    uint4* dst = (uint4*)(Xh + ((size_t)(b * 65536 + h * 256 + ww)) * 32);
    #pragma unroll
    for (int kk = 0; kk < 4; ++kk) dst[kk] = pk[kk].u;
}

// Implicit-GEMM conv: 16h x 32w px tile, 512 threads (8 waves), all 64 O.
// LDS xt[slot(4)][px(720=20x36)] uint4, slot-plane pad 1 uint4 (46.1 KB).
// Grid is b-major (round-3 order): co-resident blocks walk the same batch
// region, halos/ks stay hot in L2; no batch-XCD pinning (L3 fits all inputs).
__global__ __launch_bounds__(512, 4) void conv_hwc_kernel(const __half* __restrict__ Xh,
                                                          const __half* __restrict__ ksh,
                                                          float* __restrict__ out) {
    __shared__ uint4 xt[4 * 721];    // 46144 B

    int bid = blockIdx.x;
    int b   = bid >> 7;              // 8 batches, b-major
    int rem = bid & 127;             // 0..127
    int h0  = (rem >> 3) << 4;       // 16 h-strips of 16
    int w0  = (rem & 7) << 5;        // 8 w-strips of 32
    int tid = threadIdx.x;

    const char* Xb = (const char*)Xh + (size_t)b * ((size_t)65536 * 64);

    // ---- stage 720 px * 64 B ----
    for (int p = tid; p < 720; p += 512) {
        int r = p / 36, c = p - (p / 36) * 36;
        int gh = h0 + r - 2;
        int gw = w0 + c - 2;
        uint4 v0 = make_uint4(0u, 0u, 0u, 0u), v1 = v0, v2 = v0, v3 = v0;
        if ((unsigned)gh < 256u && (unsigned)gw < 256u) {
            const uint4* s = (const uint4*)(Xb + ((size_t)(gh * 256 + gw)) * 64);
            v0 = s[0]; v1 = s[1]; v2 = s[2]; v3 = s[3];
        }
        xt[0 * 721 + p] = v0;
        xt[1 * 721 + p] = v1;
        xt[2 * 721 + p] = v2;
        xt[3 * 721 + p] = v3;
    }
    __syncthreads();

    int wave = tid >> 6, lane = tid & 63;
    int lO = lane & 15, ks4 = lane >> 4;
    int bidx = lO * 4 + ks4;
    const uint4* ksq = (const uint4*)ksh;

    f32x4 acc[4][4] = {};
    int baseA[4];
    #pragma unroll
    for (int q = 0; q < 4; ++q)
        baseA[q] = 721 * ks4 + (wave * 2 + (q >> 1)) * 36 + (q & 1) * 16 + lO;

    // ---- 25-tap fully-unrolled MFMA loop, A/B prefetch double-buffer ----
    f16x8 Af[2][4], Bf[2][4];
    #pragma unroll
    for (int q = 0; q < 4; ++q)
        Af[0][q] = __builtin_bit_cast(f16x8, xt[baseA[q]]);
    #pragma unroll
    for (int n = 0; n < 4; ++n)
        Bf[0][n] = __builtin_bit_cast(f16x8, ksq[n * 64 + bidx]);

    #pragma unroll
    for (int t = 0; t < 25; ++t) {
        const int cur = t & 1, nxt = cur ^ 1;
        if (t < 24) {
            const int t1 = t + 1;
            const int aoff = (t1 / 5) * 36 + (t1 % 5);
            #pragma unroll
            for (int q = 0; q < 4; ++q)
                Af[nxt][q] = __builtin_bit_cast(f16x8, xt[baseA[q] + aoff]);
            #pragma unroll
            for (int n = 0; n < 4; ++n)
                Bf[nxt][n] = __builtin_bit_cast(f16x8, ksq[t1 * 256 + n * 64 + bidx]);
        }
        __builtin_amdgcn_s_setprio(1);
        #pragma unroll
        for (int q = 0; q < 4; ++q) {
            #pragma unroll
            for (int n = 0; n < 4; ++n)
                acc[q][n] = __builtin_amdgcn_mfma_f32_16x16x32_f16(Af[cur][q], Bf[cur][n], acc[q][n], 0, 0, 0);
        }
        __builtin_amdgcn_s_setprio(0);
    }

    // ---- store: out[b][O&7][O>>3][h][w] * (2pi/8); nontemporal full-line stores ----
    #pragma unroll
    for (int q = 0; q < 4; ++q) {
        int gh  = h0 + wave * 2 + (q >> 1);
        int gwb = w0 + (q & 1) * 16 + ks4 * 4;
        #pragma unroll
        for (int n = 0; n < 4; ++n) {
            int O = n * 16 + lO;
            float* op = out + (((size_t)(b * 8 + (O & 7)) * 8 + (O >> 3)) << 16)
                            + gh * 256 + gwb;
            f32x4 v = acc[q][n] * PI4_F;
            __builtin_nontemporal_store(v, (f32x4*)op);
        }
    }
}

// ---- fallback (small ws): round-3 single-kernel conv reading f32 X ----
__global__ __launch_bounds__(512, 4) void conv_kernel_f32(const float* __restrict__ X,
                                                          const __half* __restrict__ ksh,
                                                          float* __restrict__ out) {
    __shared__ uint4 xt[720 * 5];
    int blk = blockIdx.x;
    int b = blk >> 7;
    int rem = blk & 127;
    int h0 = (rem >> 3) << 4;
    int w0 = (rem & 7) << 5;
    int tid = threadIdx.x;
    const float* Xb = X + (size_t)b * 32 * 65536;
    for (int lin = tid; lin < 2880; lin += 512) {
        int slotq = lin / 720;
        int pxi = lin - slotq * 720;
        int r = pxi / 36;
        int c = pxi - r * 36;
        int gh = h0 + r - 2;
        int gw = w0 + c - 2;
        union { __half h[8]; uint4 u; } pk;
        if ((unsigned)gh < 256u && (unsigned)gw < 256u) {
            const float* src = Xb + (size_t)slotq * 8 * 65536 + gh * 256 + gw;
            #pragma unroll
            for (int j = 0; j < 8; ++j) pk.h[j] = __float2half(src[j * 65536]);
        } else {
            pk.u = make_uint4(0u, 0u, 0u, 0u);
        }
        xt[pxi * 5 + slotq] = pk.u;
    }
    __syncthreads();
    int wave = tid >> 6, lane = tid & 63;
    int lO = lane & 15, ks4 = lane >> 4;
    const uint4* ksq = (const uint4*)ksh;
    int bidx = lO * 4 + ks4;
    f32x4 acc[4][4] = {};
    int baseA[4];
    #pragma unroll
    for (int q = 0; q < 4; ++q)
        baseA[q] = ((wave * 2 + (q >> 1)) * 36 + (q & 1) * 16 + lO) * 5 + ks4;
    f16x8 Bf[2][4];
    #pragma unroll
    for (int n = 0; n < 4; ++n)
        Bf[0][n] = __builtin_bit_cast(f16x8, ksq[n * 64 + bidx]);
    #pragma unroll
    for (int t = 0; t < 25; ++t) {
        const int cur = t & 1, nxt = cur ^ 1;
        f16x8 Af[4];
        #pragma unroll
        for (int q = 0; q < 4; ++q)
            Af[q] = __builtin_bit_cast(f16x8, xt[baseA[q] + ((t / 5) * 36 + (t % 5)) * 5]);
        if (t < 24) {
            #pragma unroll
            for (int n = 0; n < 4; ++n)
                Bf[nxt][n] = __builtin_bit_cast(f16x8, ksq[(t + 1) * 256 + n * 64 + bidx]);
        }
        #pragma unroll
        for (int q = 0; q < 4; ++q)
            #pragma unroll
            for (int n = 0; n < 4; ++n)
                acc[q][n] = __builtin_amdgcn_mfma_f32_16x16x32_f16(Af[q], Bf[cur][n], acc[q][n], 0, 0, 0);
    }
    #pragma unroll
    for (int q = 0; q < 4; ++q) {
        int gh = h0 + wave * 2 + (q >> 1);
        int gwb = w0 + (q & 1) * 16 + ks4 * 4;
        #pragma unroll
        for (int n = 0; n < 4; ++n) {
            int O = n * 16 + lO;
            float* op = out + (((size_t)(b * 8 + (O & 7)) * 8 + (O >> 3)) << 16) + gh * 256 + gwb;
            *(f32x4*)op = acc[q][n] * PI4_F;
        }
    }
}

extern "C" void kernel_launch(void* const* d_in, const int* in_sizes, int n_in,
                              void* d_out, int out_size, void* d_ws, size_t ws_size,
                              hipStream_t stream) {
    const float* X = (const float*)d_in[0];       // (8, 4, 8, 256, 256) f32
    const float* w = (const float*)d_in[1];       // (4, 200, 8) f32
    float* outp = (float*)d_out;                  // (8, 8, 8, 256, 256) f32
    char* ws = (char*)d_ws;
    __half* ksh = (__half*)ws;                    // 102.4 KB

    build_ks_kernel<<<200, 256, 0, stream>>>(w, ksh);

    if (ws_size >= XH_OFF + XH_BYTES) {
        __half* Xh = (__half*)(ws + XH_OFF);      // 33.55 MB fp16 HWC
        hwc_kernel<<<8 * 256, 256, 0, stream>>>(X, Xh);
        conv_hwc_kernel<<<8 * 128, 512, 0, stream>>>(Xh, ksh, outp);
    } else {
        conv_kernel_f32<<<8 * 16 * 8, 512, 0, stream>>>(X, ksh, outp);
    }
}

// Round 8
// 94.961 us; speedup vs baseline: 2.2780x; 1.8328x over previous
//
#include <hip/hip_runtime.h>
#include <hip/hip_fp16.h>
#include <math.h>

#define PI_F      3.14159265358979323846f
#define TWO_PI_F  6.28318530717958647692f
#define PI4_F     0.78539816339744830962f   // pi/4 == ROT_SCALE == 2pi/8

typedef _Float16 f16x8 __attribute__((ext_vector_type(8)));
typedef float    f32x4 __attribute__((ext_vector_type(4)));

#define XH_OFF     ((size_t)1 << 20)                  // 1 MB
#define XH_BYTES   ((size_t)8 * 256 * 256 * 32 * 2)   // 33.55 MB

__device__ __forceinline__ float sgn(float t) {
    return (t > 0.f) ? 1.f : ((t < 0.f) ? -1.f : 0.f);
}

__device__ __forceinline__ float b2(float x) {
    float a = x - 0.5f;
    float b = x - 1.5f;
    float c = 1.f + 2.f * x;
    float d = 3.f + 2.f * x;
    return (-3.f * a * a * sgn(0.5f - x)
            + b * b * sgn(1.5f - x)
            - 0.75f * c * c * sgn(0.5f + x)
            + 0.25f * d * d * sgn(1.5f + x)) * 0.25f;
}

// ks_h[t][O][I] fp16.  t = dx*5+dy, O = r0*8+o, I = i*8+r
__global__ void build_ks_kernel(const float* __restrict__ w, __half* __restrict__ ksh) {
    int g = blockIdx.x * 256 + threadIdx.x;
    if (g >= 64 * 32 * 25) return;
    int O = g & 63;
    int rest = g >> 6;
    int t = rest % 25;
    int I = rest / 25;
    int r0 = O >> 3, o = O & 7;
    int i = I >> 3, r = I & 7;
    int x = t / 5, y = t % 5;

    float theta = -(float)r0 * PI4_F;
    float cth = cosf(theta), sth = sinf(theta);
    float fx = (float)(x - 2), fy = (float)(y - 2);
    float xc = fx * cth - fy * sth;
    float yc = fx * sth + fy * cth;

    float rotv[8];
    float rs = (float)r * PI4_F + theta;
    #pragma unroll
    for (int mr = 0; mr < 8; ++mr) {
        float v = (float)mr * PI4_F - rs + PI_F;
        float md = fmodf(v, TWO_PI_F);
        if (md < 0.f) md += TWO_PI_F;
        rotv[mr] = b2((md - PI_F) / PI4_F);
    }

    float sum = 0.f;
    for (int mx = 0; mx < 25; ++mx) {
        float cx = (float)(mx / 5 - 2);
        float cy = (float)(mx % 5 - 2);
        float bx = b2(cx - xc) * b2(cy - yc);
        if (bx != 0.f) {
            const float* wp = w + (size_t)(i * 200 + mx * 8) * 8 + o;
            #pragma unroll
            for (int mr = 0; mr < 8; ++mr)
                sum = fmaf(bx * rotv[mr], wp[mr * 8], sum);
        }
    }
    ksh[(size_t)(t * 64 + O) * 32 + I] = __float2half(sum);
}

// X (b,32ch,256,256) f32  ->  Xh (b,256,256,32ch) fp16.  One block per (b,h).
__global__ __launch_bounds__(256, 4) void hwc_kernel(const float* __restrict__ X,
                                                     __half* __restrict__ Xh) {
    int b = blockIdx.x >> 8;
    int h = blockIdx.x & 255;
    int ww = threadIdx.x;
    const float* Xb = X + ((size_t)b * 32) * 65536 + h * 256 + ww;

    union { __half hh[8]; uint4 u; } pk[4];
    #pragma unroll
    for (int c = 0; c < 32; ++c)
        pk[c >> 3].hh[c & 7] = __float2half(Xb[(size_t)c * 65536]);

    uint4* dst = (uint4*)(Xh + ((size_t)(b * 65536 + h * 256 + ww)) * 32);
    #pragma unroll
    for (int kk = 0; kk < 4; ++kk) dst[kk] = pk[kk].u;
}

// Implicit-GEMM conv: 32h x 32w px tile per 512-thread block (8 waves).
// LDS xt[slot(4)][1296 px (36x36 halo)] uint4, plane stride 1297 (83 KB).
// Wave owns 4 h-rows (wave*4..+3) = 8 M-tiles of 16 px, all 64 O (4 N-tiles):
// 32 MFMA per tap per wave; B (ks) reused across 8 M-tiles -> L2 B-traffic
// halves vs 16x32 tile; 1 block/CU (VGPR ~220), grid = 512 = 2 clean rounds.
__global__ __launch_bounds__(512, 2) void conv_hwc_kernel(const __half* __restrict__ Xh,
                                                          const __half* __restrict__ ksh,
                                                          float* __restrict__ out) {
    __shared__ uint4 xt[4 * 1297];   // 82.9 KB

    int bid = blockIdx.x;
    int b   = bid >> 6;              // 8 batches, b-major
    int rem = bid & 63;              // 0..63
    int h0  = (rem >> 3) << 5;       // 8 h-strips of 32
    int w0  = (rem & 7) << 5;        // 8 w-strips of 32
    int tid = threadIdx.x;

    const char* Xb = (const char*)Xh + (size_t)b * ((size_t)65536 * 64);

    // ---- stage 1296 px * 64 B ----
    for (int p = tid; p < 1296; p += 512) {
        int r = p / 36, c = p - (p / 36) * 36;
        int gh = h0 + r - 2;
        int gw = w0 + c - 2;
        uint4 v0 = make_uint4(0u, 0u, 0u, 0u), v1 = v0, v2 = v0, v3 = v0;
        if ((unsigned)gh < 256u && (unsigned)gw < 256u) {
            const uint4* s = (const uint4*)(Xb + ((size_t)(gh * 256 + gw)) * 64);
            v0 = s[0]; v1 = s[1]; v2 = s[2]; v3 = s[3];
        }
        xt[0 * 1297 + p] = v0;
        xt[1 * 1297 + p] = v1;
        xt[2 * 1297 + p] = v2;
        xt[3 * 1297 + p] = v3;
    }
    __syncthreads();

    int wave = tid >> 6, lane = tid & 63;
    int lO = lane & 15, ks4 = lane >> 4;
    int bidx = lO * 4 + ks4;
    const uint4* ksq = (const uint4*)ksh;

    f32x4 acc[8][4] = {};
    int baseA[8];
    #pragma unroll
    for (int m = 0; m < 8; ++m)
        baseA[m] = 1297 * ks4 + (wave * 4 + (m >> 1)) * 36 + (m & 1) * 16 + lO;

    // ---- 25-tap loop: fresh A reads (compiler fine-grains lgkmcnt),
    //      1-deep B prefetch double-buffer ----
    f16x8 Bf[2][4];
    #pragma unroll
    for (int n = 0; n < 4; ++n)
        Bf[0][n] = __builtin_bit_cast(f16x8, ksq[n * 64 + bidx]);

    #pragma unroll
    for (int t = 0; t < 25; ++t) {
        const int cur = t & 1, nxt = cur ^ 1;
        const int aoff = (t / 5) * 36 + (t % 5);

        f16x8 Af[8];
        #pragma unroll
        for (int m = 0; m < 8; ++m)
            Af[m] = __builtin_bit_cast(f16x8, xt[baseA[m] + aoff]);

        if (t < 24) {
            const int t1 = t + 1;
            #pragma unroll
            for (int n = 0; n < 4; ++n)
                Bf[nxt][n] = __builtin_bit_cast(f16x8, ksq[t1 * 256 + n * 64 + bidx]);
        }

        __builtin_amdgcn_s_setprio(1);
        #pragma unroll
        for (int m = 0; m < 8; ++m) {
            #pragma unroll
            for (int n = 0; n < 4; ++n)
                acc[m][n] = __builtin_amdgcn_mfma_f32_16x16x32_f16(Af[m], Bf[cur][n], acc[m][n], 0, 0, 0);
        }
        __builtin_amdgcn_s_setprio(0);
    }

    // ---- store: out[b][O&7][O>>3][h][w] * (2pi/8); full 128-B lines ----
    #pragma unroll
    for (int m = 0; m < 8; ++m) {
        int gh  = h0 + wave * 4 + (m >> 1);
        int gwb = w0 + (m & 1) * 16 + ks4 * 4;
        #pragma unroll
        for (int n = 0; n < 4; ++n) {
            int O = n * 16 + lO;
            float* op = out + (((size_t)(b * 8 + (O & 7)) * 8 + (O >> 3)) << 16)
                            + gh * 256 + gwb;
            *(f32x4*)op = acc[m][n] * PI4_F;
        }
    }
}

// ---- fallback (small ws): round-3 single-kernel conv reading f32 X ----
__global__ __launch_bounds__(512, 4) void conv_kernel_f32(const float* __restrict__ X,
                                                          const __half* __restrict__ ksh,
                                                          float* __restrict__ out) {
    __shared__ uint4 xt[720 * 5];
    int blk = blockIdx.x;
    int b = blk >> 7;
    int rem = blk & 127;
    int h0 = (rem >> 3) << 4;
    int w0 = (rem & 7) << 5;
    int tid = threadIdx.x;
    const float* Xb = X + (size_t)b * 32 * 65536;
    for (int lin = tid; lin < 2880; lin += 512) {
        int slotq = lin / 720;
        int pxi = lin - slotq * 720;
        int r = pxi / 36;
        int c = pxi - r * 36;
        int gh = h0 + r - 2;
        int gw = w0 + c - 2;
        union { __half h[8]; uint4 u; } pk;
        if ((unsigned)gh < 256u && (unsigned)gw < 256u) {
            const float* src = Xb + (size_t)slotq * 8 * 65536 + gh * 256 + gw;
            #pragma unroll
            for (int j = 0; j < 8; ++j) pk.h[j] = __float2half(src[j * 65536]);
        } else {
            pk.u = make_uint4(0u, 0u, 0u, 0u);
        }
        xt[pxi * 5 + slotq] = pk.u;
    }
    __syncthreads();
    int wave = tid >> 6, lane = tid & 63;
    int lO = lane & 15, ks4 = lane >> 4;
    const uint4* ksq = (const uint4*)ksh;
    int bidx = lO * 4 + ks4;
    f32x4 acc[4][4] = {};
    int baseA[4];
    #pragma unroll
    for (int q = 0; q < 4; ++q)
        baseA[q] = ((wave * 2 + (q >> 1)) * 36 + (q & 1) * 16 + lO) * 5 + ks4;
    f16x8 Bf[2][4];
    #pragma unroll
    for (int n = 0; n < 4; ++n)
        Bf[0][n] = __builtin_bit_cast(f16x8, ksq[n * 64 + bidx]);
    #pragma unroll
    for (int t = 0; t < 25; ++t) {
        const int cur = t & 1, nxt = cur ^ 1;
        f16x8 Af[4];
        #pragma unroll
        for (int q = 0; q < 4; ++q)
            Af[q] = __builtin_bit_cast(f16x8, xt[baseA[q] + ((t / 5) * 36 + (t % 5)) * 5]);
        if (t < 24) {
            #pragma unroll
            for (int n = 0; n < 4; ++n)
                Bf[nxt][n] = __builtin_bit_cast(f16x8, ksq[(t + 1) * 256 + n * 64 + bidx]);
        }
        #pragma unroll
        for (int q = 0; q < 4; ++q)
            #pragma unroll
            for (int n = 0; n < 4; ++n)
                acc[q][n] = __builtin_amdgcn_mfma_f32_16x16x32_f16(Af[q], Bf[cur][n], acc[q][n], 0, 0, 0);
    }
    #pragma unroll
    for (int q = 0; q < 4; ++q) {
        int gh = h0 + wave * 2 + (q >> 1);
        int gwb = w0 + (q & 1) * 16 + ks4 * 4;
        #pragma unroll
        for (int n = 0; n < 4; ++n) {
            int O = n * 16 + lO;
            float* op = out + (((size_t)(b * 8 + (O & 7)) * 8 + (O >> 3)) << 16) + gh * 256 + gwb;
            *(f32x4*)op = acc[q][n] * PI4_F;
        }
    }
}

extern "C" void kernel_launch(void* const* d_in, const int* in_sizes, int n_in,
                              void* d_out, int out_size, void* d_ws, size_t ws_size,
                              hipStream_t stream) {
    const float* X = (const float*)d_in[0];       // (8, 4, 8, 256, 256) f32
    const float* w = (const float*)d_in[1];       // (4, 200, 8) f32
    float* outp = (float*)d_out;                  // (8, 8, 8, 256, 256) f32
    char* ws = (char*)d_ws;
    __half* ksh = (__half*)ws;                    // 102.4 KB

    build_ks_kernel<<<200, 256, 0, stream>>>(w, ksh);

    if (ws_size >= XH_OFF + XH_BYTES) {
        __half* Xh = (__half*)(ws + XH_OFF);      // 33.55 MB fp16 HWC
        hwc_kernel<<<8 * 256, 256, 0, stream>>>(X, Xh);
        conv_hwc_kernel<<<8 * 64, 512, 0, stream>>>(Xh, ksh, outp);
    } else {
        conv_kernel_f32<<<8 * 16 * 8, 512, 0, stream>>>(X, ksh, outp);
    }
}